// Round 6
// baseline (253.718 us; speedup 1.0000x reference)
//
#include <hip/hip_runtime.h>

// ExtractTensorPatches: x (16,3,512,512) f32, window 16x16, stride 8x8, pad 0.
// out (16, 63*63, 3, 16, 16) f32.
//
// v6 = round-2 scatter structure with PLAIN stores (the untested A/B cell).
// Round-2 scatter used __builtin_nontemporal_store and showed 1.57x write
// amplification (300MB for a 195MB output) -> theory: nt bypasses L2, so the
// 16B fragments of each 64B line (two back-to-back instrs of one wave) never
// merged. Plain stores go through the XCD's L2 writeback: every 128B output
// region is assembled by ONE block (slots 0/1+2/3 from lanes 2pw..2pw+3 of a
// wave; patch-rows i,i+1 from the block's two input rows), so write-combining
// in L2 should be complete.
// Structure: 1 coalesced f4 load per thread (input read exactly once), <=4
// plain 16B stores (each output f4 written exactly once). No LDS, no barrier,
// 8 VGPR -> max occupancy, 12288 blocks.

#define BB 16
#define CC 3
#define HH 512
#define WW 512
#define NH 63
#define NW 63
#define NP (NH * NW)

typedef float f4 __attribute__((ext_vector_type(4)));

__global__ __launch_bounds__(256) void scatter_patches_v6(
    const float* __restrict__ x, float* __restrict__ out) {
  unsigned int blk = blockIdx.x;
  unsigned int tid = threadIdx.x;

  // 65536 float4 per (b,c) plane; 256 blocks per plane; block covers 2 rows.
  unsigned int plane = blk >> 8;                  // b*3 + c, 0..47
  unsigned int b = plane / CC;
  unsigned int c = plane - b * CC;
  unsigned int row  = ((blk & 255u) << 1) | (tid >> 7);  // 0..511
  unsigned int col4 = tid & 127u;                 // float4 column, 0..127

  const f4* src = reinterpret_cast<const f4*>(x);
  f4 v = src[(plane << 16) + (row << 7) + col4];  // 1KB/wave, coalesced

  f4* o = reinterpret_cast<f4*>(out);
  // out f4 index = ((b*NP + ph*NW + pw)*CC + c)*64 + i*4 + s
  unsigned int base = b * (NP * CC * 64u) + c * 64u;     // b*762048 + c*64

  unsigned int ph1 = row >> 3;                    // i1 = row & 7
  unsigned int i1  = row & 7u;
  unsigned int a1 = base + ph1 * (NW * CC * 64u) + (i1 << 2);
  // ph2 = ph1-1, i2 = i1+8:  a2 = a1 - 12096 + 32
  unsigned int a2 = a1 - (NW * CC * 64u) + 32u;

  unsigned int offA = (col4 >> 1) * (CC * 64u) + (col4 & 1u);  // pwA*192 + sA
  // pwB = pwA-1, sB = sA+2:  offB = offA - 192 + 2
  unsigned int offB = offA - (CC * 64u) + 2u;

  bool r1 = row < (HH - 8u);   // ph1 <= 62
  bool r2 = row >= 8u;         // ph2 >= 0
  bool ca = col4 < 126u;       // pwA <= 62
  bool cb = col4 >= 2u;        // pwB >= 0

  if (r1 & ca) o[a1 + offA] = v;
  if (r1 & cb) o[a1 + offB] = v;
  if (r2 & ca) o[a2 + offA] = v;
  if (r2 & cb) o[a2 + offB] = v;
}

extern "C" void kernel_launch(void* const* d_in, const int* in_sizes, int n_in,
                              void* d_out, int out_size, void* d_ws, size_t ws_size,
                              hipStream_t stream) {
  const float* x = (const float*)d_in[0];
  float* out = (float*)d_out;
  scatter_patches_v6<<<dim3(BB * CC * 256), 256, 0, stream>>>(x, out);
}

// Round 7
// 252.685 us; speedup vs baseline: 1.0041x; 1.0041x over previous
//
#include <hip/hip_runtime.h>

// ExtractTensorPatches: x (16,3,512,512) f32, window 16x16, stride 8x8, pad 0.
// out (16, 63*63, 3, 16, 16) f32.
//
// v7 == v6 resubmitted unchanged: round-6's container ran 22% slow (fill
// dispatches 145-147us @ 5.4 TB/s vs 117-120us @ 6.5 TB/s in all prior
// rounds), confounding the A/B. Genuine round-6 signals: plain-store scatter
// dropped out of the top-5 (<142us, vs 275us for nt-scatter in round 2) ->
// nt-bypass WAS the write-amplification cause; fill-rate-normalized total
// (253.7 * 5.4/6.5 ~= 211us) suggests scatter+plain beats the 227-231us LDS
// plateau. This run isolates container health as the only variable.
//
// Structure: 1 coalesced f4 load per thread (input read exactly once), <=4
// plain 16B stores (each output f4 written exactly once; 64B lines completed
// by back-to-back stores of one wave -> full L2 write-combining). No LDS, no
// barrier, 8 VGPR -> max occupancy, 12288 blocks.

#define BB 16
#define CC 3
#define HH 512
#define WW 512
#define NH 63
#define NW 63
#define NP (NH * NW)

typedef float f4 __attribute__((ext_vector_type(4)));

__global__ __launch_bounds__(256) void scatter_patches_v7(
    const float* __restrict__ x, float* __restrict__ out) {
  unsigned int blk = blockIdx.x;
  unsigned int tid = threadIdx.x;

  // 65536 float4 per (b,c) plane; 256 blocks per plane; block covers 2 rows.
  unsigned int plane = blk >> 8;                  // b*3 + c, 0..47
  unsigned int b = plane / CC;
  unsigned int c = plane - b * CC;
  unsigned int row  = ((blk & 255u) << 1) | (tid >> 7);  // 0..511
  unsigned int col4 = tid & 127u;                 // float4 column, 0..127

  const f4* src = reinterpret_cast<const f4*>(x);
  f4 v = src[(plane << 16) + (row << 7) + col4];  // 1KB/wave, coalesced

  f4* o = reinterpret_cast<f4*>(out);
  // out f4 index = ((b*NP + ph*NW + pw)*CC + c)*64 + i*4 + s
  unsigned int base = b * (NP * CC * 64u) + c * 64u;     // b*762048 + c*64

  unsigned int ph1 = row >> 3;                    // i1 = row & 7
  unsigned int i1  = row & 7u;
  unsigned int a1 = base + ph1 * (NW * CC * 64u) + (i1 << 2);
  // ph2 = ph1-1, i2 = i1+8:  a2 = a1 - 12096 + 32
  unsigned int a2 = a1 - (NW * CC * 64u) + 32u;

  unsigned int offA = (col4 >> 1) * (CC * 64u) + (col4 & 1u);  // pwA*192 + sA
  // pwB = pwA-1, sB = sA+2:  offB = offA - 192 + 2
  unsigned int offB = offA - (CC * 64u) + 2u;

  bool r1 = row < (HH - 8u);   // ph1 <= 62
  bool r2 = row >= 8u;         // ph2 >= 0
  bool ca = col4 < 126u;       // pwA <= 62
  bool cb = col4 >= 2u;        // pwB >= 0

  if (r1 & ca) o[a1 + offA] = v;
  if (r1 & cb) o[a1 + offB] = v;
  if (r2 & ca) o[a2 + offA] = v;
  if (r2 & cb) o[a2 + offB] = v;
}

extern "C" void kernel_launch(void* const* d_in, const int* in_sizes, int n_in,
                              void* d_out, int out_size, void* d_ws, size_t ws_size,
                              hipStream_t stream) {
  const float* x = (const float*)d_in[0];
  float* out = (float*)d_out;
  scatter_patches_v7<<<dim3(BB * CC * 256), 256, 0, stream>>>(x, out);
}